// Round 8
// baseline (2445.562 us; speedup 1.0000x reference)
//
#include <hip/hip_runtime.h>
#include <cmath>

typedef unsigned short u16;
typedef short bf16x8 __attribute__((ext_vector_type(8)));
typedef float f32x4 __attribute__((ext_vector_type(4)));

#define S_N 1025
#define W_N 128
#define H_N 200
#define FH_N 800
#define KP 232
#define SGP 911
#define MID 512
#define NT 56
#define PKT (NT * 7 * 512)
// conflict-free LDS B-fragment layout: per-kcc stride 544 u16, per-quadk 136
#define PKC 544
#define QKS 136
#define FRAGSZ (7 * PKC)

__device__ __forceinline__ float bf2f(u16 u) {
  unsigned int x = ((unsigned int)u) << 16;
  return __builtin_bit_cast(float, x);
}
__device__ __forceinline__ u16 f2bf(float f) {
  unsigned int x = __builtin_bit_cast(unsigned int, f);
  x += 0x7fffu + ((x >> 16) & 1u);
  return (u16)(x >> 16);
}
#define LOG2E 1.44269504088896f
__device__ __forceinline__ float fsigm(float x) {
  float e = __builtin_amdgcn_exp2f(-fabsf(x) * LOG2E);
  float p = __builtin_amdgcn_rcpf(1.f + e);
  return x >= 0.f ? p : 1.f - p;
}
__device__ __forceinline__ float ftanh(float x) {
  float e = __builtin_amdgcn_exp2f(-2.f * fabsf(x) * LOG2E);
  float th = (1.f - e) * __builtin_amdgcn_rcpf(1.f + e);
  return x >= 0.f ? th : -th;
}

// interleaved gate order: packed row r' = 4*unit + gatetype  ->  src row
__device__ __forceinline__ int gperm(int rp) { return (rp & 3) * H_N + (rp >> 2); }

__device__ __forceinline__ const bf16x8* pkptr(const u16* pk, int tt, int kcc, int lane) {
  return (const bf16x8*)(pk + (size_t)((tt * 7 + kcc) * 512 + lane * 8));
}
// writer: element (row m 0..15, k 0..223) -> padded LDS fragment index
__device__ __forceinline__ int fidx(int m, int k) {
  return (k >> 5) * PKC + ((k >> 3) & 3) * QKS + m * 8 + (k & 7);
}
// reader: lane's 16B fragment for k-chunk kcc
__device__ __forceinline__ const bf16x8* frg(const u16* base, int kcc, int lane) {
  return (const bf16x8*)(base + kcc * PKC + (lane >> 4) * QKS + (lane & 15) * 8);
}

// ---------------------------------------------------------------------------
// Kernel 0: repack 8 fp32 weight matrices to bf16 MFMA fragment order with
// INTERLEAVED gate rows (r' = 4u+g). dst:
// [wih_ctx|whh_ctx|wih_tgt|whh_tgt|whh_prev|whh_post|wih_prev|wih_post]
// ---------------------------------------------------------------------------
__global__ __launch_bounds__(256) void k_w2b(
    const float* __restrict__ p0, const float* __restrict__ p1,
    const float* __restrict__ p2, const float* __restrict__ p3,
    const float* __restrict__ p4, const float* __restrict__ p5,
    const float* __restrict__ p6, const float* __restrict__ p7,
    u16* __restrict__ dst)
{
  int i = blockIdx.x * 256 + threadIdx.x;
  if (i >= 8 * PKT) return;
  int w = i / PKT, r = i - w * PKT;
  int tt = r / 3584;
  int q = r - tt * 3584;
  int kcc = q >> 9;
  int lane = (q >> 3) & 63;
  int j = q & 7;
  int col = lane & 15, quad = lane >> 4;
  int gate = tt * 16 + col;          // permuted row index
  int k = kcc * 32 + quad * 8 + j;
  const float* ps[8] = {p0, p1, p2, p3, p4, p5, p6, p7};
  u16 v = 0;
  if (gate < FH_N && k < H_N) v = f2bf(ps[w][(size_t)gperm(gate) * H_N + k]);
  dst[i] = v;
}

// ---------------------------------------------------------------------------
// Kernel 0b: bitonic sort of sentence ids by length (desc) -> order[]
// ---------------------------------------------------------------------------
__global__ __launch_bounds__(1024) void k_sort(
    const int* __restrict__ lengths, int* __restrict__ order)
{
  __shared__ int key[2048], val[2048];
  int tid = threadIdx.x;
  for (int v = 0; v < 2; ++v) {
    int i = tid + v * 1024;
    key[i] = (i < S_N) ? lengths[i] : -1;
    val[i] = (i < S_N) ? i : (S_N - 1);
  }
  __syncthreads();
  for (int k = 2; k <= 2048; k <<= 1)
    for (int j = k >> 1; j > 0; j >>= 1) {
      for (int v = 0; v < 2; ++v) {
        int i = tid + v * 1024;
        int ix = i ^ j;
        if (ix > i) {
          bool descRegion = ((i & k) == 0);
          int ki = key[i], kx = key[ix];
          if ((ki < kx) == descRegion) {
            key[i] = kx; key[ix] = ki;
            int tv = val[i]; val[i] = val[ix]; val[ix] = tv;
          }
        }
      }
      __syncthreads();
    }
  for (int v = 0; v < 2; ++v) {
    int i = tid + v * 1024;
    if (i < S_N) order[i] = val[i];
  }
}

// ---------------------------------------------------------------------------
// Kernel X: chunked input-projection GEMM, one block per slot (handles all
// t-tiles of the chunk; weights loaded once per kcc for both tiles).
// gxc[slot][tc][gate'] (permuted gate order).
// ---------------------------------------------------------------------------
__global__ __launch_bounds__(512, 1) void k_xpack(
    int c, int CH,
    const float* __restrict__ words, const int* __restrict__ lengths,
    const u16* __restrict__ wihb_ctx, const float* __restrict__ bih_ctx, const float* __restrict__ bhh_ctx,
    const u16* __restrict__ wihb_tgt, const float* __restrict__ bih_tgt, const float* __restrict__ bhh_tgt,
    float* __restrict__ gxc)
{
  const int slot = blockIdx.x;
  const bool tg = (slot == 1025);
  const int s = tg ? MID : slot;
  const int len = lengths[s];
  const int tb0 = c * CH;
  if (tb0 >= len) return;
  const u16* wih = tg ? wihb_tgt : wihb_ctx;
  const float* bih = tg ? bih_tgt : bih_ctx;
  const float* bhh = tg ? bhh_tgt : bhh_ctx;

  __shared__ __align__(16) u16 sXh[2][FRAGSZ];
  __shared__ __align__(16) u16 sXl[2][FRAGSZ];
  __shared__ float sBias[FH_N];
  const int tid = threadIdx.x;
  for (int e = tid; e < FRAGSZ; e += 512) {
    sXh[0][e] = 0; sXl[0][e] = 0; sXh[1][e] = 0; sXl[1][e] = 0;
  }
  for (int e = tid; e < FH_N; e += 512) sBias[e] = bih[gperm(e)] + bhh[gperm(e)];
  __syncthreads();

  const int nt = min(2, (min(CH, len - tb0) + 15) >> 4);
  for (int jt = 0; jt < nt; ++jt) {
    int nrow = min(16, min(CH - jt * 16, len - tb0 - jt * 16));
    for (int e = tid; e < nrow * H_N; e += 512) {
      int tr = e / H_N, k = e - tr * H_N;
      float v = words[((size_t)s * W_N + tb0 + jt * 16 + tr) * H_N + k];
      u16 vh = f2bf(v);
      int idx = fidx(tr, k);
      sXh[jt][idx] = vh;
      sXl[jt][idx] = f2bf(v - bf2f(vh));
    }
  }
  __syncthreads();

  const int lane = tid & 63, wv = tid >> 6, quad = lane >> 4, col = lane & 15;
  f32x4 acc[2][7];
#pragma unroll
  for (int jt = 0; jt < 2; ++jt)
#pragma unroll
    for (int i = 0; i < 7; ++i) { f32x4 z = {0.f, 0.f, 0.f, 0.f}; acc[jt][i] = z; }

#pragma unroll
  for (int kcc = 0; kcc < 7; ++kcc) {
    bf16x8 Aw[7];
#pragma unroll
    for (int i = 0; i < 7; ++i) Aw[i] = *pkptr(wih, wv + 8 * i, kcc, lane);
#pragma unroll
    for (int jt = 0; jt < 2; ++jt) {
      if (jt < nt) {
        bf16x8 bxh = *frg(sXh[jt], kcc, lane);
        bf16x8 bxl = *frg(sXl[jt], kcc, lane);
#pragma unroll
        for (int i = 0; i < 7; ++i) {
          acc[jt][i] = __builtin_amdgcn_mfma_f32_16x16x32_bf16(Aw[i], bxh, acc[jt][i], 0, 0, 0);
          acc[jt][i] = __builtin_amdgcn_mfma_f32_16x16x32_bf16(Aw[i], bxl, acc[jt][i], 0, 0, 0);
        }
      }
    }
  }

#pragma unroll
  for (int jt = 0; jt < 2; ++jt) {
    if (jt < nt) {
      int tcg = jt * 16 + col;
      bool ok = (tcg < CH) && (tb0 + tcg < len);
      if (ok) {
#pragma unroll
        for (int i = 0; i < 7; ++i) {
          int tt = wv + 8 * i;
          if (tt < 50) {
            float b0 = sBias[tt * 16 + quad * 4 + 0];
            float b1 = sBias[tt * 16 + quad * 4 + 1];
            float b2 = sBias[tt * 16 + quad * 4 + 2];
            float b3 = sBias[tt * 16 + quad * 4 + 3];
            f32x4 o = {acc[jt][i][0] + b0, acc[jt][i][1] + b1,
                       acc[jt][i][2] + b2, acc[jt][i][3] + b3};
            *(f32x4*)(gxc + ((size_t)slot * CH + tcg) * FH_N + tt * 16 + quad * 4) = o;
          }
        }
      }
    }
  }
}

// ---------------------------------------------------------------------------
// Kernel R: chunked word recurrence, interleaved gates. Lane (quad,col) owns
// unit 4*tt+quad of sentence col for its 7 tiles: cell update fully in
// registers; h written to double-buffered fragment LDS; ONE barrier/step.
// ---------------------------------------------------------------------------
__global__ __launch_bounds__(512, 1) void k_wrec(
    int c, int CH,
    const int* __restrict__ lengths, const int* __restrict__ order,
    const float* __restrict__ h0w, const float* __restrict__ c0w,
    const u16* __restrict__ whhb_ctx, const u16* __restrict__ whhb_tgt,
    const float* __restrict__ gxc,
    float* __restrict__ stateH, float* __restrict__ stateC,
    float* __restrict__ emb)
{
  const int tid = threadIdx.x;
  const int b = blockIdx.x;
  const bool is_tgt = (b == 65);
  const u16* whh = is_tgt ? whhb_tgt : whhb_ctx;

  __shared__ __align__(16) u16 sBh[2][FRAGSZ];
  __shared__ __align__(16) u16 sBl[2][FRAGSZ];
  __shared__ int sLen[16], sId[16];

  if (tid < 16) {
    int slot = b * 16 + tid;
    int s = is_tgt ? MID : order[min(slot, S_N - 1)];
    sId[tid] = s;
    sLen[tid] = lengths[s];
  }
  for (int e = tid; e < FRAGSZ; e += 512) {
    sBh[0][e] = 0; sBl[0][e] = 0; sBh[1][e] = 0; sBl[1][e] = 0;
  }
  __syncthreads();
  int Lmax = 1;
  for (int m = 0; m < 16; ++m) Lmax = max(Lmax, sLen[m]);
  if (c * CH >= Lmax) return;

  const int lane = tid & 63;
  const int wv = tid >> 6;
  const int quad = lane >> 4;
  const int col = lane & 15;
  const int myS = sId[col];
  const int myLen = sLen[col];

  bf16x8 afr[7][7];
#pragma unroll
  for (int i = 0; i < 7; ++i)
#pragma unroll
    for (int kcc = 0; kcc < 7; ++kcc)
      afr[i][kcc] = *pkptr(whh, wv + 8 * i, kcc, lane);

  // per-lane state: unit uu_i = 4*(wv+8i)+quad of sentence col
  float creg[7], hreg[7];
#pragma unroll
  for (int i = 0; i < 7; ++i) {
    int uu = 4 * (wv + 8 * i) + quad;
    if (uu < H_N) {
      if (c == 0) {
        hreg[i] = h0w[(size_t)myS * H_N + uu];
        creg[i] = c0w[(size_t)myS * H_N + uu];
      } else {
        hreg[i] = stateH[(size_t)(b * 16 + col) * H_N + uu];
        creg[i] = stateC[(size_t)(b * 16 + col) * H_N + uu];
      }
      u16 hh = f2bf(hreg[i]);
      int idx = fidx(col, uu);
      sBh[0][idx] = hh;
      sBl[0][idx] = f2bf(hreg[i] - bf2f(hh));
    } else { creg[i] = 0.f; hreg[i] = 0.f; }
  }
  __syncthreads();

#pragma unroll 1
  for (int tc = 0; tc < CH; ++tc) {
    const int t = c * CH + tc;
    if (t >= Lmax) break;
    const int cb = tc & 1, nb = cb ^ 1;
    const int gslot = is_tgt ? 1025 : myS;
    const float* gbase = gxc + ((size_t)gslot * CH + tc) * FH_N;

    // gx for this lane's 7 units (4 contiguous permuted gates each)
    f32x4 gv[7];
#pragma unroll
    for (int i = 0; i < 7; ++i) {
      int uu = 4 * (wv + 8 * i) + quad;
      if (uu < H_N) gv[i] = *(const f32x4*)(gbase + 4 * uu);
    }

    f32x4 acc[7];
#pragma unroll
    for (int i = 0; i < 7; ++i) { f32x4 z = {0.f, 0.f, 0.f, 0.f}; acc[i] = z; }
#pragma unroll
    for (int kcc = 0; kcc < 7; ++kcc) {
      bf16x8 bh = *frg(sBh[cb], kcc, lane);
      bf16x8 bl = *frg(sBl[cb], kcc, lane);
#pragma unroll
      for (int i = 0; i < 7; ++i) {
        acc[i] = __builtin_amdgcn_mfma_f32_16x16x32_bf16(afr[i][kcc], bh, acc[i], 0, 0, 0);
        acc[i] = __builtin_amdgcn_mfma_f32_16x16x32_bf16(afr[i][kcc], bl, acc[i], 0, 0, 0);
      }
    }

#pragma unroll
    for (int i = 0; i < 7; ++i) {
      int uu = 4 * (wv + 8 * i) + quad;
      if (uu < H_N) {
        float ig = acc[i][0] + gv[i][0];
        float fg = acc[i][1] + gv[i][1];
        float gg = acc[i][2] + gv[i][2];
        float og = acc[i][3] + gv[i][3];
        float nc = fsigm(fg) * creg[i] + fsigm(ig) * ftanh(gg);
        float nh = fsigm(og) * ftanh(nc);
        creg[i] = nc;
        hreg[i] = nh;
        u16 hh = f2bf(nh);
        int idx = fidx(col, uu);
        sBh[nb][idx] = hh;
        sBl[nb][idx] = f2bf(nh - bf2f(hh));
        if (t == myLen - 1) {
          if (is_tgt) {
            if (col == 0) emb[(size_t)MID * H_N + uu] = nh;
          } else if (myS != MID) {
            emb[(size_t)myS * H_N + uu] = nh;
          }
        }
      }
    }
    __syncthreads();
  }

#pragma unroll
  for (int i = 0; i < 7; ++i) {
    int uu = 4 * (wv + 8 * i) + quad;
    if (uu < H_N) {
      stateH[(size_t)(b * 16 + col) * H_N + uu] = hreg[i];
      stateC[(size_t)(b * 16 + col) * H_N + uu] = creg[i];
    }
  }
}

// ---------------------------------------------------------------------------
// Fallback (tiny ws): streaming word kernel, permuted-gate aware.
// ---------------------------------------------------------------------------
__global__ __launch_bounds__(512, 1) void k_word_s(
    const float* __restrict__ words, const int* __restrict__ lengths,
    const int* __restrict__ order,
    const float* __restrict__ h0w, const float* __restrict__ c0w,
    const u16* __restrict__ wihb_ctx, const u16* __restrict__ whhb_ctx,
    const float* __restrict__ bih_ctx, const float* __restrict__ bhh_ctx,
    const u16* __restrict__ wihb_tgt, const u16* __restrict__ whhb_tgt,
    const float* __restrict__ bih_tgt, const float* __restrict__ bhh_tgt,
    float* __restrict__ emb)
{
  const int tid = threadIdx.x;
  const int b = blockIdx.x;
  const bool is_tgt = (b == 65);
  const u16* wih = is_tgt ? wihb_tgt : wihb_ctx;
  const u16* whh = is_tgt ? whhb_tgt : whhb_ctx;
  const float* bih = is_tgt ? bih_tgt : bih_ctx;
  const float* bhh = is_tgt ? bhh_tgt : bhh_ctx;

  __shared__ __align__(16) u16 sXhi[16 * KP];
  __shared__ __align__(16) u16 sXlo[16 * KP];
  __shared__ __align__(16) u16 sHi[16 * KP];
  __shared__ __align__(16) u16 sLo[16 * KP];
  __shared__ float sG[8 * SGP];
  __shared__ float sB[4 * H_N];
  __shared__ int sLen[16], sId[16];

  for (int e = tid; e < 16 * KP; e += 512) {
    sXhi[e] = 0; sXlo[e] = 0; sHi[e] = 0; sLo[e] = 0;
  }
  if (tid < 16) {
    int slot = b * 16 + tid;
    int s = is_tgt ? MID : order[min(slot, S_N - 1)];
    sId[tid] = s;
    sLen[tid] = lengths[s];
  }
  for (int e = tid; e < 4 * H_N; e += 512) sB[e] = bih[gperm(e)] + bhh[gperm(e)];
  __syncthreads();

  float creg[7];
#pragma unroll
  for (int r = 0; r < 7; ++r) {
    int e = tid + 512 * r;
    if (e < 16 * H_N) {
      int m = e / H_N, j = e - m * H_N;
      int s = sId[m];
      float h = h0w[(size_t)s * H_N + j];
      u16 hh = f2bf(h);
      sHi[m * KP + j] = hh;
      sLo[m * KP + j] = f2bf(h - bf2f(hh));
      creg[r] = c0w[(size_t)s * H_N + j];
    }
  }
  __syncthreads();
  int Lmax = 1;
  for (int m = 0; m < 16; ++m) Lmax = max(Lmax, sLen[m]);

  const int lane = tid & 63;
  const int wv = tid >> 6;
  const int quad = lane >> 4;
  const int col = lane & 15;
  const int hpass = quad >> 1;

  const u16* aXh = sXhi + col * KP + quad * 8;
  const u16* aXl = sXlo + col * KP + quad * 8;
  const u16* aHh = sHi  + col * KP + quad * 8;
  const u16* aHl = sLo  + col * KP + quad * 8;

#pragma unroll 1
  for (int t = 0; t < Lmax; ++t) {
    for (int e = tid; e < 16 * H_N; e += 512) {
      int m = e / H_N, k = e - m * H_N;
      float v = words[((size_t)sId[m] * W_N + t) * H_N + k];
      u16 vh = f2bf(v);
      sXhi[m * KP + k] = vh;
      sXlo[m * KP + k] = f2bf(v - bf2f(vh));
    }
    __syncthreads();

    f32x4 acc[7];
#pragma unroll
    for (int i = 0; i < 7; ++i) { f32x4 z4 = {0.f, 0.f, 0.f, 0.f}; acc[i] = z4; }

#pragma unroll
    for (int kcc = 0; kcc < 7; ++kcc) {
      bf16x8 axh = *(const bf16x8*)(aXh + kcc * 32);
      bf16x8 axl = *(const bf16x8*)(aXl + kcc * 32);
      bf16x8 ahh = *(const bf16x8*)(aHh + kcc * 32);
      bf16x8 ahl = *(const bf16x8*)(aHl + kcc * 32);
#pragma unroll
      for (int i = 0; i < 7; ++i) {
        bf16x8 bw = *pkptr(wih, wv + 8 * i, kcc, lane);
        bf16x8 bh = *pkptr(whh, wv + 8 * i, kcc, lane);
        acc[i] = __builtin_amdgcn_mfma_f32_16x16x32_bf16(axh, bw, acc[i], 0, 0, 0);
        acc[i] = __builtin_amdgcn_mfma_f32_16x16x32_bf16(axl, bw, acc[i], 0, 0, 0);
        acc[i] = __builtin_amdgcn_mfma_f32_16x16x32_bf16(ahh, bh, acc[i], 0, 0, 0);
        acc[i] = __builtin_amdgcn_mfma_f32_16x16x32_bf16(ahl, bh, acc[i], 0, 0, 0);
      }
    }

#pragma unroll 1
    for (int h = 0; h < 2; ++h) {
      if (hpass == h) {
#pragma unroll
        for (int i = 0; i < 7; ++i) {
          int tt = wv + 8 * i;
#pragma unroll
          for (int r = 0; r < 4; ++r)
            sG[((quad & 1) * 4 + r) * SGP + tt * 16 + col] = acc[i][r];
        }
      }
      __syncthreads();
#pragma unroll
      for (int rr = 0; rr < 7; ++rr) {
        int e = tid + 512 * rr;
        if (e < 16 * H_N) {
          int m = e / H_N, j = e - m * H_N;
          if ((m >> 3) == h) {
            const float* gRow = sG + (m - 8 * h) * SGP + 4 * j;
            float ig = gRow[0] + sB[4 * j + 0];
            float fg = gRow[1] + sB[4 * j + 1];
            float gg = gRow[2] + sB[4 * j + 2];
            float og = gRow[3] + sB[4 * j + 3];
            float nc = fsigm(fg) * creg[rr] + fsigm(ig) * ftanh(gg);
            float nh = fsigm(og) * ftanh(nc);
            creg[rr] = nc;
            u16 hh = f2bf(nh);
            sHi[m * KP + j] = hh;
            sLo[m * KP + j] = f2bf(nh - bf2f(hh));
            if (t == sLen[m] - 1) {
              int s = sId[m];
              if (is_tgt) {
                if (m == 0) emb[(size_t)MID * H_N + j] = nh;
              } else if (s != MID) {
                emb[(size_t)s * H_N + j] = nh;
              }
            }
          }
        }
      }
      __syncthreads();
    }
  }
}

// ---------------------------------------------------------------------------
// Kernel 2: gx projections for prev/post (permuted gate order output).
// ---------------------------------------------------------------------------
__global__ __launch_bounds__(512) void k_gx(
    const float* __restrict__ emb,
    const u16* __restrict__ wihb_prev, const float* __restrict__ bih_prev, const float* __restrict__ bhh_prev,
    const u16* __restrict__ wihb_post, const float* __restrict__ bih_post, const float* __restrict__ bhh_post,
    float* __restrict__ gxp, float* __restrict__ gxq)
{
  const int tid = threadIdx.x;
  const int b = blockIdx.x;
  const bool post = (b >= 33);
  const int t0 = (post ? b - 33 : b) * 16;
  const u16* wih = post ? wihb_post : wihb_prev;
  const float* bih = post ? bih_post : bih_prev;
  const float* bhh = post ? bhh_post : bhh_prev;
  float* out = post ? gxq : gxp;

  __shared__ __align__(16) u16 sEhi[16 * KP];
  __shared__ __align__(16) u16 sElo[16 * KP];
  for (int e = tid; e < 16 * KP; e += 512) { sEhi[e] = 0; sElo[e] = 0; }
  __syncthreads();
  for (int e = tid; e < 16 * H_N; e += 512) {
    int m = e / H_N, k = e - m * H_N;
    int t = t0 + m;
    if (t <= 512) {
      int src = post ? (1024 - t) : t;
      float v = emb[(size_t)src * H_N + k];
      u16 vh = f2bf(v);
      sEhi[m * KP + k] = vh;
      sElo[m * KP + k] = f2bf(v - bf2f(vh));
    }
  }
  __syncthreads();

  const int lane = tid & 63;
  const int wv = tid >> 6;
  const int quad = lane >> 4;
  const int col = lane & 15;
  const u16* aH = sEhi + col * KP + quad * 8;
  const u16* aL = sElo + col * KP + quad * 8;

#pragma unroll 1
  for (int i = 0; i < 7; ++i) {
    int tt = wv + 8 * i;
    if (tt >= 50) break;
    int gate = tt * 16 + col;          // permuted index
    f32x4 acc = {0.f, 0.f, 0.f, 0.f};
#pragma unroll
    for (int kcc = 0; kcc < 7; ++kcc) {
      bf16x8 Ah = *(const bf16x8*)(aH + kcc * 32);
      bf16x8 Al = *(const bf16x8*)(aL + kcc * 32);
      bf16x8 bw = *pkptr(wih, tt, kcc, lane);
      acc = __builtin_amdgcn_mfma_f32_16x16x32_bf16(Ah, bw, acc, 0, 0, 0);
      acc = __builtin_amdgcn_mfma_f32_16x16x32_bf16(Al, bw, acc, 0, 0, 0);
    }
    float bias = bih[gperm(gate)] + bhh[gperm(gate)];
#pragma unroll
    for (int r = 0; r < 4; ++r) {
      int t = t0 + quad * 4 + r;
      if (t <= 512) out[(size_t)t * FH_N + gate] = acc[r] + bias;
    }
  }
}

// ---------------------------------------------------------------------------
// Kernel 3: prev/post sentence LSTMs with interleaved gates. One barrier per
// step; mixed B (cols 0..7 h_hi / 8..15 h_lo); lane (quad,col<7) updates unit
// 4*(wv+8col)+quad fully in registers. Double-buffered h.
// ---------------------------------------------------------------------------
__global__ __launch_bounds__(512, 1) void k_sent(
    const u16* __restrict__ whhb_prev, const u16* __restrict__ whhb_post,
    const float* __restrict__ h0p, const float* __restrict__ c0p,
    const float* __restrict__ h0q, const float* __restrict__ c0q,
    const float* __restrict__ gxp, const float* __restrict__ gxq,
    float* __restrict__ outp, float* __restrict__ outq)
{
  const int tid = threadIdx.x;
  const bool post = (blockIdx.x != 0);
  const u16* whh = post ? whhb_post : whhb_prev;
  const float* h0 = post ? h0q : h0p;
  const float* c0 = post ? c0q : c0p;
  const float* gx = post ? gxq : gxp;
  float* outv = post ? outq : outp;

  __shared__ __align__(16) u16 sHi[2][224];
  __shared__ __align__(16) u16 sLo[2][224];

  const int lane = tid & 63;
  const int wv = tid >> 6;
  const int quad = lane >> 4;
  const int col = lane & 15;

  bf16x8 afr[7][7];
#pragma unroll
  for (int i = 0; i < 7; ++i)
#pragma unroll
    for (int kcc = 0; kcc < 7; ++kcc)
      afr[i][kcc] = *pkptr(whh, wv + 8 * i, kcc, lane);

  if (tid < 224) { sHi[0][tid] = 0; sLo[0][tid] = 0; sHi[1][tid] = 0; sLo[1][tid] = 0; }
  if (tid < H_N) {
    float h = h0[tid];
    u16 hh = f2bf(h);
    sHi[0][tid] = hh;
    sLo[0][tid] = f2bf(h - bf2f(hh));
  }

  // this lane's update assignment: tile utile = wv + 8*col (col<7)
  const int utile = wv + 8 * col;
  const bool upd = (col < 7) && (utile < 50);
  const int uu = 4 * utile + quad;
  float c = upd ? c0[uu] : 0.f;
  float last_h = 0.f;
  f32x4 gcur = {0.f, 0.f, 0.f, 0.f};
  if (upd) gcur = *(const f32x4*)(gx + 4 * uu);
  __syncthreads();

#pragma unroll 1
  for (int t = 0; t < 513; ++t) {
    const int cb = t & 1, nb = cb ^ 1;
    const u16* hb = ((lane & 8) ? sLo[cb] : sHi[cb]) + quad * 8;
    bf16x8 bfr[7];
#pragma unroll
    for (int kcc = 0; kcc < 7; ++kcc) bfr[kcc] = *(const bf16x8*)(hb + kcc * 32);

    // prefetch next step's gx (drains during MFMA phase)
    f32x4 gnext = {0.f, 0.f, 0.f, 0.f};
    if (t + 1 < 513 && upd) gnext = *(const f32x4*)(gx + (size_t)(t + 1) * FH_N + 4 * uu);

    f32x4 acc[7];
#pragma unroll
    for (int i = 0; i < 7; ++i) { f32x4 z = {0.f, 0.f, 0.f, 0.f}; acc[i] = z; }
#pragma unroll
    for (int kcc = 0; kcc < 7; ++kcc)
#pragma unroll
      for (int i = 0; i < 7; ++i)
        acc[i] = __builtin_amdgcn_mfma_f32_16x16x32_bf16(afr[i][kcc], bfr[kcc], acc[i], 0, 0, 0);

    // combine hi+lo across col^8 and select this lane's tile
    f32x4 gsel = {0.f, 0.f, 0.f, 0.f};
#pragma unroll
    for (int i = 0; i < 7; ++i) {
      f32x4 w;
#pragma unroll
      for (int r = 0; r < 4; ++r) w[r] = acc[i][r] + __shfl_xor(acc[i][r], 8);
      if (col == i) gsel = w;
    }

    if (upd) {
      float ig = gsel[0] + gcur[0];
      float fg = gsel[1] + gcur[1];
      float gg = gsel[2] + gcur[2];
      float og = gsel[3] + gcur[3];
      float nc = fsigm(fg) * c + fsigm(ig) * ftanh(gg);
      float nh = fsigm(og) * ftanh(nc);
      c = nc;
      last_h = nh;
      u16 hh = f2bf(nh);
      sHi[nb][uu] = hh;
      sLo[nb][uu] = f2bf(nh - bf2f(hh));
    }
    gcur = gnext;
    __syncthreads();
  }
  if (upd) outv[uu] = last_h;
}

// ---------------------------------------------------------------------------
// Kernel 4: out = [prev_out ; post_out] @ fc_w^T + fc_b
// ---------------------------------------------------------------------------
__global__ __launch_bounds__(256) void k_fc(
    const float* __restrict__ pout, const float* __restrict__ qout,
    const float* __restrict__ fc_w, const float* __restrict__ fc_b,
    float* __restrict__ out)
{
  const int tid = threadIdx.x;
  if (tid < H_N) {
    float d = fc_b[tid];
    const float* wr = fc_w + (size_t)tid * 2 * H_N;
    for (int k = 0; k < H_N; ++k) d += pout[k] * wr[k];
    for (int k = 0; k < H_N; ++k) d += qout[k] * wr[H_N + k];
    out[tid] = d;
  }
}

extern "C" void kernel_launch(void* const* d_in, const int* in_sizes, int n_in,
                              void* d_out, int out_size, void* d_ws, size_t ws_size,
                              hipStream_t stream) {
  const float* words   = (const float*)d_in[0];
  const int*   lengths = (const int*)d_in[1];
  const float* h0w = (const float*)d_in[2];
  const float* c0w = (const float*)d_in[3];
  const float* h0p = (const float*)d_in[4];
  const float* c0p = (const float*)d_in[5];
  const float* h0q = (const float*)d_in[6];
  const float* c0q = (const float*)d_in[7];
  const float* wih_ctx = (const float*)d_in[8];
  const float* whh_ctx = (const float*)d_in[9];
  const float* bih_ctx = (const float*)d_in[10];
  const float* bhh_ctx = (const float*)d_in[11];
  const float* wih_tgt = (const float*)d_in[12];
  const float* whh_tgt = (const float*)d_in[13];
  const float* bih_tgt = (const float*)d_in[14];
  const float* bhh_tgt = (const float*)d_in[15];
  const float* wih_prev = (const float*)d_in[16];
  const float* whh_prev = (const float*)d_in[17];
  const float* bih_prev = (const float*)d_in[18];
  const float* bhh_prev = (const float*)d_in[19];
  const float* wih_post = (const float*)d_in[20];
  const float* whh_post = (const float*)d_in[21];
  const float* bih_post = (const float*)d_in[22];
  const float* bhh_post = (const float*)d_in[23];
  const float* fc_w = (const float*)d_in[24];
  const float* fc_b = (const float*)d_in[25];
  (void)in_sizes; (void)n_in; (void)out_size;

  const size_t FIXF = 1448600;
  int CH = 0;
  for (int cand = 32; cand >= 1; cand >>= 1) {
    size_t needB = ((size_t)1026 * cand * 800 + FIXF) * 4 + 1056 * 4 + (size_t)8 * PKT * 2 + 256;
    if (ws_size >= needB) { CH = cand; break; }
  }

  float* ws = (float*)d_ws;
  float *gxc, *stateH, *stateC, *emb, *gxp, *gxq, *po, *qo;
  int* order;
  u16* wb;
  if (CH > 0) {
    gxc = ws;
    stateH = gxc + (size_t)1026 * CH * 800;
    stateC = stateH + 211200;
    emb = stateC + 211200;
    gxp = emb + 205000;
    gxq = gxp + 410400;
    po = gxq + 410400;
    qo = po + 200;
    order = (int*)(qo + 200);
    wb = (u16*)(order + 1056);
  } else {
    gxc = nullptr; stateH = nullptr; stateC = nullptr;
    emb = ws;
    gxp = ws + 205000;
    gxq = ws + 615400;
    po = ws + 1025800;
    qo = ws + 1026000;
    order = (int*)(ws + 1026200);
    wb = (u16*)(ws + 1027232);
  }
  u16* wihb_ctx  = wb;
  u16* whhb_ctx  = wb + PKT;
  u16* wihb_tgt  = wb + 2 * PKT;
  u16* whhb_tgt  = wb + 3 * PKT;
  u16* whhb_prev = wb + 4 * PKT;
  u16* whhb_post = wb + 5 * PKT;
  u16* wihb_prev = wb + 6 * PKT;
  u16* wihb_post = wb + 7 * PKT;

  k_w2b<<<(8 * PKT + 255) / 256, 256, 0, stream>>>(
      wih_ctx, whh_ctx, wih_tgt, whh_tgt, whh_prev, whh_post,
      wih_prev, wih_post, wb);
  k_sort<<<1, 1024, 0, stream>>>(lengths, order);

  if (CH > 0) {
    const int NC = (W_N + CH - 1) / CH;
    for (int c = 0; c < NC; ++c) {
      k_xpack<<<1026, 512, 0, stream>>>(c, CH, words, lengths,
                                        wihb_ctx, bih_ctx, bhh_ctx,
                                        wihb_tgt, bih_tgt, bhh_tgt, gxc);
      k_wrec<<<66, 512, 0, stream>>>(c, CH, lengths, order, h0w, c0w,
                                     whhb_ctx, whhb_tgt, gxc, stateH, stateC, emb);
    }
  } else {
    k_word_s<<<66, 512, 0, stream>>>(words, lengths, order, h0w, c0w,
                                     wihb_ctx, whhb_ctx, bih_ctx, bhh_ctx,
                                     wihb_tgt, whhb_tgt, bih_tgt, bhh_tgt, emb);
  }
  k_gx<<<66, 512, 0, stream>>>(emb, wihb_prev, bih_prev, bhh_prev,
                               wihb_post, bih_post, bhh_post, gxp, gxq);
  k_sent<<<2, 512, 0, stream>>>(whhb_prev, whhb_post, h0p, c0p, h0q, c0q,
                                gxp, gxq, po, qo);
  k_fc<<<1, 256, 0, stream>>>(po, qo, fc_w, fc_b, (float*)d_out);
}